// Round 7
// baseline (67892.657 us; speedup 1.0000x reference)
//
#include <hip/hip_runtime.h>
#include <stdint.h>

#define B_GRAPHS 4096
#define NPG 40
#define NTOT (B_GRAPHS * NPG)      // 163840
#define EPG 160
#define ETOT (B_GRAPHS * EPG)      // 655360
#define ESL 200                    // 160 edges + 40 self-loop slots
#define F_IN 78
#define HID 128
#define D0 512
#define CMB 520
#define BN_EPS 1e-5f

// Diagnostic: out[0] = code (float), rest 0 — visible as absmax ~ code
__global__ __launch_bounds__(256)
void write_code_kernel(float* __restrict__ out, int n, float S)
{
    int i = blockIdx.x * 256 + threadIdx.x;
    if (i < n) out[i] = (i == 0) ? S : 0.f;
}

// ---------------------------------------------------------------------------
// Naive GEMM: C[M,N] = A[M,K] @ B[K,N], all fp32
// ---------------------------------------------------------------------------
__global__ __launch_bounds__(256)
void gemm_kernel(const float* __restrict__ A, const float* __restrict__ Bm,
                 float* __restrict__ C, int M, int K, int N)
{
    int idx = blockIdx.x * 256 + threadIdx.x;
    if (idx >= M * N) return;
    int row = idx / N, col = idx - row * N;
    const float* arow = A + (size_t)row * K;
    float acc = 0.f;
    for (int k = 0; k < K; k++)
        acc += arow[k] * Bm[(size_t)k * N + col];
    C[idx] = acc;
}

// ---------------------------------------------------------------------------
// Attention logits: one thread per (local node, head). H fp32 [nloc, heads*ch]
// ---------------------------------------------------------------------------
__global__ __launch_bounds__(256)
void att_logits_kernel(const float* __restrict__ H,
                       const float* __restrict__ avs, const float* __restrict__ avd,
                       float* __restrict__ ES, float* __restrict__ ED,
                       int nloc, int heads, int ch)
{
    int t = blockIdx.x * 256 + threadIdx.x;
    if (t >= nloc * heads) return;
    int node = t / heads, h = t - node * heads;
    const float* row = H + (size_t)node * (heads * ch) + h * ch;
    float a = 0.f, b = 0.f;
    for (int c = 0; c < ch; c++) {
        float hv = row[c];
        a += hv * avs[h * ch + c];
        b += hv * avd[h * ch + c];
    }
    ES[t] = a; ED[t] = b;
}

// ---------------------------------------------------------------------------
// Softmax alpha: one thread per (local dst node, head); scans 200 slots.
// ALPHA [chunk * 200 * heads]
// ---------------------------------------------------------------------------
__global__ __launch_bounds__(256)
void att_alpha_kernel(const int* __restrict__ edge,
                      const float* __restrict__ ES, const float* __restrict__ ED,
                      float* __restrict__ ALPHA, int chunk, int g0, int heads)
{
    int t = blockIdx.x * 256 + threadIdx.x;
    if (t >= chunk * NPG * heads) return;
    int h = t % heads, dloc = t / heads;
    int g = dloc / NPG, dn = dloc - g * NPG;
    int gg = g0 + g;
    const int* esrc = edge + (size_t)gg * EPG;
    const int* edst = esrc + ETOT;
    const int base = gg * NPG;
    float edv = ED[(size_t)dloc * heads + h];

    float m = -1e30f;
    for (int e = 0; e < ESL; e++) {
        int s, dd;
        if (e < EPG) { s = esrc[e] - base; dd = edst[e] - base; }
        else         { s = dd = e - EPG; }
        if (dd != dn) continue;
        float v = ES[(size_t)(g * NPG + s) * heads + h] + edv;
        v = v > 0.f ? v : 0.2f * v;
        m = fmaxf(m, v);
    }
    float den = 0.f;
    for (int e = 0; e < ESL; e++) {
        int s, dd;
        if (e < EPG) { s = esrc[e] - base; dd = edst[e] - base; }
        else         { s = dd = e - EPG; }
        if (dd != dn) continue;
        float v = ES[(size_t)(g * NPG + s) * heads + h] + edv;
        v = v > 0.f ? v : 0.2f * v;
        float ex = __expf(v - m);
        ALPHA[(size_t)(g * ESL + e) * heads + h] = ex;
        den += ex;
    }
    float inv = 1.f / den;
    for (int e = 0; e < ESL; e++) {
        int dd;
        if (e < EPG) { dd = edst[e] - base; }
        else         { dd = e - EPG; }
        if (dd != dn) continue;
        ALPHA[(size_t)(g * ESL + e) * heads + h] *= inv;
    }
}

// ---------------------------------------------------------------------------
// Aggregation + bias + BN (+ReLU): one thread per (dst node, channel), fp32.
// ---------------------------------------------------------------------------
__global__ __launch_bounds__(256)
void att_agg_kernel(const float* __restrict__ H, const int* __restrict__ edge,
                    const float* __restrict__ ALPHA,
                    const float* __restrict__ bias, const float* __restrict__ bng,
                    const float* __restrict__ bnb, const float* __restrict__ bnm,
                    const float* __restrict__ bnv,
                    float* __restrict__ OUT,
                    int chunk, int g0, int heads, int ch, int do_relu)
{
    const int C = heads * ch;
    int t = blockIdx.x * 256 + threadIdx.x;
    if (t >= chunk * NPG * C) return;
    int c = t % C, d = t / C;
    int g = d / NPG, dn = d - g * NPG;
    int gg = g0 + g, h = c / ch;
    const int* esrc = edge + (size_t)gg * EPG;
    const int* edst = esrc + ETOT;
    const int base = gg * NPG;
    float acc = 0.f;
    for (int e = 0; e < ESL; e++) {
        int s, dd;
        if (e < EPG) { s = esrc[e] - base; dd = edst[e] - base; }
        else         { s = dd = e - EPG; }
        if (dd != dn) continue;
        acc += ALPHA[(size_t)(g * ESL + e) * heads + h]
             * H[(size_t)(g * NPG + s) * C + c];
    }
    float o = acc + bias[c];
    o = (o - bnm[c]) * rsqrtf(bnv[c] + BN_EPS) * bng[c] + bnb[c];
    if (do_relu) o = fmaxf(o, 0.f);
    OUT[t] = o;
}

// ---------------------------------------------------------------------------
// Pool: mean/max over 40 nodes of OB fp32 [chunk*40,128] -> cmb [B,512]
// ---------------------------------------------------------------------------
__global__ __launch_bounds__(256)
void pool_kernel(const float* __restrict__ OB, float* __restrict__ cmb,
                 int chunk, int g0, int colbase)
{
    int t = blockIdx.x * 256 + threadIdx.x;
    if (t >= chunk * 2 * HID) return;
    int g = t / (2 * HID), r = t - g * (2 * HID);
    int which = r / HID, c = r - which * HID;
    int gg = g0 + g;
    const float* basep = OB + (size_t)g * NPG * HID + c;
    if (!which) {
        float s = 0.f;
        for (int i = 0; i < NPG; i++) s += basep[(size_t)i * HID];
        cmb[(size_t)gg * 512 + colbase + c] = s * (1.f / NPG);
    } else {
        float m = -1e30f;
        for (int i = 0; i < NPG; i++) m = fmaxf(m, basep[(size_t)i * HID]);
        cmb[(size_t)gg * 512 + colbase + HID + c] = m;
    }
}

// ---------------------------------------------------------------------------
// Final MLP: [520] -> 256 (BN,ReLU) -> 128 (BN,ReLU) -> 1 (sigmoid), fp32
// ---------------------------------------------------------------------------
__global__ __launch_bounds__(256)
void mlp_kernel(const float* __restrict__ cmb, const float* __restrict__ addf,
                const float* __restrict__ W0, const float* __restrict__ b0,
                const float* __restrict__ g0v, const float* __restrict__ be0,
                const float* __restrict__ m0, const float* __restrict__ v0,
                const float* __restrict__ W1, const float* __restrict__ b1,
                const float* __restrict__ g1v, const float* __restrict__ be1,
                const float* __restrict__ m1, const float* __restrict__ v1,
                const float* __restrict__ W2, const float* __restrict__ b2,
                float* __restrict__ out)
{
    __shared__ float c[CMB];
    __shared__ float h1[256];
    __shared__ float h2[128];
    const int g = blockIdx.x, tid = threadIdx.x;
    for (int i = tid; i < 512; i += 256) c[i] = cmb[(size_t)g * 512 + i];
    if (tid < 8) c[512 + tid] = addf[g * 8 + tid];
    __syncthreads();
    {
        int j = tid;
        float acc = b0[j];
        for (int k = 0; k < CMB; k++) acc += c[k] * W0[k * 256 + j];
        acc = (acc - m0[j]) * rsqrtf(v0[j] + BN_EPS) * g0v[j] + be0[j];
        h1[j] = fmaxf(acc, 0.f);
    }
    __syncthreads();
    if (tid < 128) {
        int j = tid;
        float acc = b1[j];
        for (int k = 0; k < 256; k++) acc += h1[k] * W1[k * 128 + j];
        acc = (acc - m1[j]) * rsqrtf(v1[j] + BN_EPS) * g1v[j] + be1[j];
        h2[j] = fmaxf(acc, 0.f);
    }
    __syncthreads();
    if (tid == 0) {
        float acc = b2[0];
        for (int k = 0; k < 128; k++) acc += h2[k] * W2[k];
        out[g] = 1.f / (1.f + __expf(-acc));
    }
}

// ---------------------------------------------------------------------------
extern "C" void kernel_launch(void* const* d_in, const int* in_sizes, int n_in,
                              void* d_out, int out_size, void* d_ws, size_t ws_size,
                              hipStream_t stream)
{
    static const int expect[45] = {
        12779520, 1310720, 163840, 12779520, 1310720, 163840, 32768,
        39936, 512, 512, 512,
        262144, 512, 512, 512,
        65536, 128, 128, 128,
        512, 512, 512, 512,
        512, 512, 512, 512,
        128, 128, 128, 128,
        133120, 256, 256, 256, 256, 256,
        32768, 128, 128, 128, 128, 128,
        128, 1 };

    float* out = (float*)d_out;
    int out_n = out_size < 4096 ? out_size : 4096;

    // guards (codes visible as absmax ~= code, now that out is f32)
    float S = -1.f;
    if (n_in != 45) S = 100000.f + (n_in > 0 && n_in < 1000 ? n_in : 999);
    else if (out_size != 4096) S = 200000.f + (out_size > 0 && out_size < 65536 ? out_size : 65535);
    else {
        for (int i = 0; i < 45; i++)
            if (in_sizes[i] != expect[i]) { S = 1000.f + 10.f * i; break; }
    }
    if (S >= 0.f) {
        write_code_kernel<<<(out_n + 255) / 256, 256, 0, stream>>>(out, out_n, S);
        return;
    }

    const float* x_a  = (const float*)d_in[0];
    const int*   edge_a = (const int*)d_in[1];
    const float* x_b  = (const float*)d_in[3];
    const int*   edge_b = (const int*)d_in[4];
    const float* addf = (const float*)d_in[6];
    const float* gW0 = (const float*)d_in[7],  *gb0 = (const float*)d_in[8];
    const float* gas0 = (const float*)d_in[9], *gad0 = (const float*)d_in[10];
    const float* gW1 = (const float*)d_in[11], *gb1 = (const float*)d_in[12];
    const float* gas1 = (const float*)d_in[13], *gad1 = (const float*)d_in[14];
    const float* gW2 = (const float*)d_in[15], *gb2 = (const float*)d_in[16];
    const float* gas2 = (const float*)d_in[17], *gad2 = (const float*)d_in[18];
    const float* bn0g = (const float*)d_in[19], *bn0b = (const float*)d_in[20];
    const float* bn0m = (const float*)d_in[21], *bn0v = (const float*)d_in[22];
    const float* bn1g = (const float*)d_in[23], *bn1b = (const float*)d_in[24];
    const float* bn1m = (const float*)d_in[25], *bn1v = (const float*)d_in[26];
    const float* bn2g = (const float*)d_in[27], *bn2b = (const float*)d_in[28];
    const float* bn2m = (const float*)d_in[29], *bn2v = (const float*)d_in[30];
    const float* mW0 = (const float*)d_in[31], *mb0 = (const float*)d_in[32];
    const float* mg0 = (const float*)d_in[33], *mbe0 = (const float*)d_in[34];
    const float* mm0 = (const float*)d_in[35], *mv0 = (const float*)d_in[36];
    const float* mW1 = (const float*)d_in[37], *mb1 = (const float*)d_in[38];
    const float* mg1 = (const float*)d_in[39], *mbe1 = (const float*)d_in[40];
    const float* mm1 = (const float*)d_in[41], *mv1 = (const float*)d_in[42];
    const float* mW2 = (const float*)d_in[43], *mb2 = (const float*)d_in[44];

    // workspace: cmb (8 MB) + chunk * {B1, B2, ES, ED, ALPHA} all fp32
    char* p = (char*)d_ws;
    const size_t CMB_BYTES = (size_t)B_GRAPHS * 512 * sizeof(float);
    float* cmb = (float*)p; p += CMB_BYTES;
    const size_t PG = 81920ull + 81920ull + 640ull + 640ull + 3200ull; // 168,320
    size_t used = CMB_BYTES;
    int chunk = B_GRAPHS;
    while (chunk > 4 && used + (size_t)chunk * PG > ws_size) chunk >>= 1;
    if (used + (size_t)chunk * PG > ws_size) {
        write_code_kernel<<<(out_n + 255) / 256, 256, 0, stream>>>(out, out_n, 500000.f);
        return;
    }
    float* B1 = (float*)p;    p += (size_t)chunk * 81920;
    float* B2 = (float*)p;    p += (size_t)chunk * 81920;
    float* ES = (float*)p;    p += (size_t)chunk * 640;
    float* ED = (float*)p;    p += (size_t)chunk * 640;
    float* ALPHA = (float*)p;

    for (int drug = 0; drug < 2; drug++) {
        const float* x = drug ? x_b : x_a;
        const int* edge = drug ? edge_b : edge_a;
        int colbase = drug ? 256 : 0;

        for (int g0 = 0; g0 < B_GRAPHS; g0 += chunk) {
            int n = chunk * NPG;
            // layer 0: x[g0*40 ...] @ gW0 -> B1 ; GAT -> B2
            gemm_kernel<<<(n * D0 + 255) / 256, 256, 0, stream>>>(
                x + (size_t)g0 * NPG * F_IN, gW0, B1, n, F_IN, D0);
            att_logits_kernel<<<(n * 4 + 255) / 256, 256, 0, stream>>>(
                B1, gas0, gad0, ES, ED, n, 4, HID);
            att_alpha_kernel<<<(n * 4 + 255) / 256, 256, 0, stream>>>(
                edge, ES, ED, ALPHA, chunk, g0, 4);
            att_agg_kernel<<<(n * D0 + 255) / 256, 256, 0, stream>>>(
                B1, edge, ALPHA, gb0, bn0g, bn0b, bn0m, bn0v,
                B2, chunk, g0, 4, HID, 1);
            // layer 1: B2 @ gW1 -> B1 ; GAT -> B2
            gemm_kernel<<<(n * D0 + 255) / 256, 256, 0, stream>>>(
                B2, gW1, B1, n, D0, D0);
            att_logits_kernel<<<(n * 4 + 255) / 256, 256, 0, stream>>>(
                B1, gas1, gad1, ES, ED, n, 4, HID);
            att_alpha_kernel<<<(n * 4 + 255) / 256, 256, 0, stream>>>(
                edge, ES, ED, ALPHA, chunk, g0, 4);
            att_agg_kernel<<<(n * D0 + 255) / 256, 256, 0, stream>>>(
                B1, edge, ALPHA, gb1, bn1g, bn1b, bn1m, bn1v,
                B2, chunk, g0, 4, HID, 1);
            // layer 2: B2 @ gW2 -> B1[:,0:128] ; GAT1 -> B2 (no relu) ; pool
            gemm_kernel<<<(n * HID + 255) / 256, 256, 0, stream>>>(
                B2, gW2, B1, n, D0, HID);
            att_logits_kernel<<<(n + 255) / 256, 256, 0, stream>>>(
                B1, gas2, gad2, ES, ED, n, 1, HID);
            att_alpha_kernel<<<(n + 255) / 256, 256, 0, stream>>>(
                edge, ES, ED, ALPHA, chunk, g0, 1);
            att_agg_kernel<<<(n * HID + 255) / 256, 256, 0, stream>>>(
                B1, edge, ALPHA, gb2, bn2g, bn2b, bn2m, bn2v,
                B2, chunk, g0, 1, HID, 0);
            pool_kernel<<<(chunk * 2 * HID + 255) / 256, 256, 0, stream>>>(
                B2, cmb, chunk, g0, colbase);
        }
    }
    mlp_kernel<<<B_GRAPHS, 256, 0, stream>>>(
        cmb, addf, mW0, mb0, mg0, mbe0, mm0, mv0,
        mW1, mb1, mg1, mbe1, mm1, mv1, mW2, mb2, out);
}

// Round 8
// 29407.761 us; speedup vs baseline: 2.3087x; 2.3087x over previous
//
#include <hip/hip_runtime.h>
#include <stdint.h>

#define B_GRAPHS 4096
#define NPG 40
#define NTOT (B_GRAPHS * NPG)      // 163840
#define EPG 160
#define ETOT (B_GRAPHS * EPG)      // 655360
#define ESL 200                    // 160 edges + 40 self-loop slots
#define F_IN 78
#define KP0 96                     // F_IN padded to multiple of 32
#define HID 128
#define D0 512
#define CMB 520
#define BN_EPS 1e-5f

typedef short bf16x8 __attribute__((ext_vector_type(8)));
typedef float floatx4 __attribute__((ext_vector_type(4)));

__device__ inline float b2f(unsigned short u) {
    union { float f; uint32_t i; } v; v.i = ((uint32_t)u) << 16; return v.f;
}
__device__ inline unsigned short f2b(float f) {
    union { float f; uint32_t i; } v; v.f = f;
    uint32_t x = v.i;
    return (unsigned short)((x + 0x7fffu + ((x >> 16) & 1u)) >> 16);
}

__global__ __launch_bounds__(256)
void write_code_kernel(float* __restrict__ out, int n, float S)
{
    int i = blockIdx.x * 256 + threadIdx.x;
    if (i < n) out[i] = (i == 0) ? S : 0.f;
}

// ---------------------------------------------------------------------------
// Weight convert: W [K,N] fp32 -> Wt [N,Kp] bf16 (transposed, zero-padded K)
// ---------------------------------------------------------------------------
__global__ __launch_bounds__(256)
void convw_kernel(const float* __restrict__ W, unsigned short* __restrict__ Wt,
                  int K, int N, int Kp)
{
    int t = blockIdx.x * 256 + threadIdx.x;
    if (t >= N * Kp) return;
    int n = t / Kp, k = t - n * Kp;
    Wt[t] = (k < K) ? f2b(W[(size_t)k * N + n]) : 0;
}

// x convert: X [M,78] fp32 -> Xb [M,96] bf16 zero-padded
__global__ __launch_bounds__(256)
void convx_kernel(const float* __restrict__ X, unsigned short* __restrict__ Xb, int M)
{
    int t = blockIdx.x * 256 + threadIdx.x;
    if (t >= M * KP0) return;
    int r = t / KP0, k = t - r * KP0;
    Xb[t] = (k < F_IN) ? f2b(X[(size_t)r * F_IN + k]) : 0;
}

// ---------------------------------------------------------------------------
// MFMA GEMM: C[M,N] = A[M,K] @ Bt[N,K]^T, bf16 in, bf16 out, fp32 accum.
// 64x64 tile, BK=32, 4 waves. K % 32 == 0. M guarded.
// A frag: m=lane&15, k=quad*8+j ; B frag: n=lane&15, k=quad*8+j
// C/D:    col=lane&15, row=quad*4+reg            [HW-verified layouts]
// ---------------------------------------------------------------------------
__global__ __launch_bounds__(256)
void gemm_mfma_kernel(const unsigned short* __restrict__ A,
                      const unsigned short* __restrict__ Bt,
                      unsigned short* __restrict__ C,
                      int M, int K, int N)
{
    __shared__ __align__(16) unsigned short As[64 * 32];
    __shared__ __align__(16) unsigned short Bs[64 * 32];
    const int tid  = threadIdx.x;
    const int lane = tid & 63, wave = tid >> 6;
    const int quad = lane >> 4, l16 = lane & 15;
    const int row0 = blockIdx.y * 64, col0 = blockIdx.x * 64;

    floatx4 acc0 = {0.f,0.f,0.f,0.f}, acc1 = {0.f,0.f,0.f,0.f};
    floatx4 acc2 = {0.f,0.f,0.f,0.f}, acc3 = {0.f,0.f,0.f,0.f};

    const int r = tid >> 2, kk = (tid & 3) * 8;       // staging coords
    for (int k0 = 0; k0 < K; k0 += 32) {
        // A tile 64x32 (row-guarded)
        if (row0 + r < M) {
            uint4 v = *(const uint4*)(A + (size_t)(row0 + r) * K + k0 + kk);
            *(uint4*)(&As[r * 32 + kk]) = v;
        } else {
            *(uint4*)(&As[r * 32 + kk]) = make_uint4(0, 0, 0, 0);
        }
        // B tile 64x32 from Bt [N,K] (cols always in range)
        {
            uint4 v = *(const uint4*)(Bt + (size_t)(col0 + r) * K + k0 + kk);
            *(uint4*)(&Bs[r * 32 + kk]) = v;
        }
        __syncthreads();

        bf16x8 a, b0, b1, b2v, b3;
        __builtin_memcpy(&a,   &As[(wave * 16 + l16) * 32 + quad * 8], 16);
        __builtin_memcpy(&b0,  &Bs[( 0 + l16) * 32 + quad * 8], 16);
        __builtin_memcpy(&b1,  &Bs[(16 + l16) * 32 + quad * 8], 16);
        __builtin_memcpy(&b2v, &Bs[(32 + l16) * 32 + quad * 8], 16);
        __builtin_memcpy(&b3,  &Bs[(48 + l16) * 32 + quad * 8], 16);
        acc0 = __builtin_amdgcn_mfma_f32_16x16x32_bf16(a, b0,  acc0, 0, 0, 0);
        acc1 = __builtin_amdgcn_mfma_f32_16x16x32_bf16(a, b1,  acc1, 0, 0, 0);
        acc2 = __builtin_amdgcn_mfma_f32_16x16x32_bf16(a, b2v, acc2, 0, 0, 0);
        acc3 = __builtin_amdgcn_mfma_f32_16x16x32_bf16(a, b3,  acc3, 0, 0, 0);
        __syncthreads();
    }
    const int orow = row0 + wave * 16 + quad * 4;
    #pragma unroll
    for (int rr = 0; rr < 4; rr++) {
        if (orow + rr >= M) break;
        size_t base = (size_t)(orow + rr) * N + col0 + l16;
        C[base +  0] = f2b(acc0[rr]);
        C[base + 16] = f2b(acc1[rr]);
        C[base + 32] = f2b(acc2[rr]);
        C[base + 48] = f2b(acc3[rr]);
    }
}

// ---------------------------------------------------------------------------
// Attention logits: H bf16 [nloc, heads*ch]; avs/avd fp32 (raw inputs)
// ---------------------------------------------------------------------------
__global__ __launch_bounds__(256)
void att_logits_kernel(const unsigned short* __restrict__ H,
                       const float* __restrict__ avs, const float* __restrict__ avd,
                       float* __restrict__ ES, float* __restrict__ ED,
                       int nloc, int heads, int ch)
{
    int t = blockIdx.x * 256 + threadIdx.x;
    if (t >= nloc * heads) return;
    int node = t / heads, h = t - node * heads;
    const unsigned short* row = H + (size_t)node * (heads * ch) + h * ch;
    float a = 0.f, b = 0.f;
    for (int c = 0; c < ch; c++) {
        float hv = b2f(row[c]);
        a += hv * avs[h * ch + c];
        b += hv * avd[h * ch + c];
    }
    ES[t] = a; ED[t] = b;
}

// ---------------------------------------------------------------------------
// Softmax alpha: one thread per (local dst node, head); scans 200 slots.
// ---------------------------------------------------------------------------
__global__ __launch_bounds__(256)
void att_alpha_kernel(const int* __restrict__ edge,
                      const float* __restrict__ ES, const float* __restrict__ ED,
                      float* __restrict__ ALPHA, int chunk, int g0, int heads)
{
    int t = blockIdx.x * 256 + threadIdx.x;
    if (t >= chunk * NPG * heads) return;
    int h = t % heads, dloc = t / heads;
    int g = dloc / NPG, dn = dloc - g * NPG;
    int gg = g0 + g;
    const int* esrc = edge + (size_t)gg * EPG;
    const int* edst = esrc + ETOT;
    const int base = gg * NPG;
    float edv = ED[(size_t)dloc * heads + h];

    float m = -1e30f;
    for (int e = 0; e < ESL; e++) {
        int s, dd;
        if (e < EPG) { s = esrc[e] - base; dd = edst[e] - base; }
        else         { s = dd = e - EPG; }
        if (dd != dn) continue;
        float v = ES[(size_t)(g * NPG + s) * heads + h] + edv;
        v = v > 0.f ? v : 0.2f * v;
        m = fmaxf(m, v);
    }
    float den = 0.f;
    for (int e = 0; e < ESL; e++) {
        int s, dd;
        if (e < EPG) { s = esrc[e] - base; dd = edst[e] - base; }
        else         { s = dd = e - EPG; }
        if (dd != dn) continue;
        float v = ES[(size_t)(g * NPG + s) * heads + h] + edv;
        v = v > 0.f ? v : 0.2f * v;
        float ex = __expf(v - m);
        ALPHA[(size_t)(g * ESL + e) * heads + h] = ex;
        den += ex;
    }
    float inv = 1.f / den;
    for (int e = 0; e < ESL; e++) {
        int dd;
        if (e < EPG) { dd = edst[e] - base; }
        else         { dd = e - EPG; }
        if (dd != dn) continue;
        ALPHA[(size_t)(g * ESL + e) * heads + h] *= inv;
    }
}

// ---------------------------------------------------------------------------
// Aggregation + bias + BN (+ReLU): H bf16; OUT bf16 or OUTF fp32.
// ---------------------------------------------------------------------------
__global__ __launch_bounds__(256)
void att_agg_kernel(const unsigned short* __restrict__ H, const int* __restrict__ edge,
                    const float* __restrict__ ALPHA,
                    const float* __restrict__ bias, const float* __restrict__ bng,
                    const float* __restrict__ bnb, const float* __restrict__ bnm,
                    const float* __restrict__ bnv,
                    unsigned short* __restrict__ OUT, float* __restrict__ OUTF,
                    int chunk, int g0, int heads, int ch, int do_relu)
{
    const int C = heads * ch;
    int t = blockIdx.x * 256 + threadIdx.x;
    if (t >= chunk * NPG * C) return;
    int c = t % C, d = t / C;
    int g = d / NPG, dn = d - g * NPG;
    int gg = g0 + g, h = c / ch;
    const int* esrc = edge + (size_t)gg * EPG;
    const int* edst = esrc + ETOT;
    const int base = gg * NPG;
    float acc = 0.f;
    for (int e = 0; e < ESL; e++) {
        int s, dd;
        if (e < EPG) { s = esrc[e] - base; dd = edst[e] - base; }
        else         { s = dd = e - EPG; }
        if (dd != dn) continue;
        acc += ALPHA[(size_t)(g * ESL + e) * heads + h]
             * b2f(H[(size_t)(g * NPG + s) * C + c]);
    }
    float o = acc + bias[c];
    o = (o - bnm[c]) * rsqrtf(bnv[c] + BN_EPS) * bng[c] + bnb[c];
    if (do_relu) o = fmaxf(o, 0.f);
    if (OUT) OUT[t] = f2b(o);
    else     OUTF[t] = o;
}

// ---------------------------------------------------------------------------
// Pool: mean/max over 40 nodes of OB fp32 [chunk*40,128] -> cmb [B,512]
// ---------------------------------------------------------------------------
__global__ __launch_bounds__(256)
void pool_kernel(const float* __restrict__ OB, float* __restrict__ cmb,
                 int chunk, int g0, int colbase)
{
    int t = blockIdx.x * 256 + threadIdx.x;
    if (t >= chunk * 2 * HID) return;
    int g = t / (2 * HID), r = t - g * (2 * HID);
    int which = r / HID, c = r - which * HID;
    int gg = g0 + g;
    const float* basep = OB + (size_t)g * NPG * HID + c;
    if (!which) {
        float s = 0.f;
        for (int i = 0; i < NPG; i++) s += basep[(size_t)i * HID];
        cmb[(size_t)gg * 512 + colbase + c] = s * (1.f / NPG);
    } else {
        float m = -1e30f;
        for (int i = 0; i < NPG; i++) m = fmaxf(m, basep[(size_t)i * HID]);
        cmb[(size_t)gg * 512 + colbase + HID + c] = m;
    }
}

// ---------------------------------------------------------------------------
// Final MLP: [520] -> 256 (BN,ReLU) -> 128 (BN,ReLU) -> 1 (sigmoid), fp32
// ---------------------------------------------------------------------------
__global__ __launch_bounds__(256)
void mlp_kernel(const float* __restrict__ cmb, const float* __restrict__ addf,
                const float* __restrict__ W0, const float* __restrict__ b0,
                const float* __restrict__ g0v, const float* __restrict__ be0,
                const float* __restrict__ m0, const float* __restrict__ v0,
                const float* __restrict__ W1, const float* __restrict__ b1,
                const float* __restrict__ g1v, const float* __restrict__ be1,
                const float* __restrict__ m1, const float* __restrict__ v1,
                const float* __restrict__ W2, const float* __restrict__ b2,
                float* __restrict__ out)
{
    __shared__ float c[CMB];
    __shared__ float h1[256];
    __shared__ float h2[128];
    const int g = blockIdx.x, tid = threadIdx.x;
    for (int i = tid; i < 512; i += 256) c[i] = cmb[(size_t)g * 512 + i];
    if (tid < 8) c[512 + tid] = addf[g * 8 + tid];
    __syncthreads();
    {
        int j = tid;
        float acc = b0[j];
        for (int k = 0; k < CMB; k++) acc += c[k] * W0[k * 256 + j];
        acc = (acc - m0[j]) * rsqrtf(v0[j] + BN_EPS) * g0v[j] + be0[j];
        h1[j] = fmaxf(acc, 0.f);
    }
    __syncthreads();
    if (tid < 128) {
        int j = tid;
        float acc = b1[j];
        for (int k = 0; k < 256; k++) acc += h1[k] * W1[k * 128 + j];
        acc = (acc - m1[j]) * rsqrtf(v1[j] + BN_EPS) * g1v[j] + be1[j];
        h2[j] = fmaxf(acc, 0.f);
    }
    __syncthreads();
    if (tid == 0) {
        float acc = b2[0];
        for (int k = 0; k < 128; k++) acc += h2[k] * W2[k];
        out[g] = 1.f / (1.f + __expf(-acc));
    }
}

// ---------------------------------------------------------------------------
extern "C" void kernel_launch(void* const* d_in, const int* in_sizes, int n_in,
                              void* d_out, int out_size, void* d_ws, size_t ws_size,
                              hipStream_t stream)
{
    float* out = (float*)d_out;
    int out_n = out_size < 4096 ? out_size : 4096;

    const float* x_a  = (const float*)d_in[0];
    const int*   edge_a = (const int*)d_in[1];
    const float* x_b  = (const float*)d_in[3];
    const int*   edge_b = (const int*)d_in[4];
    const float* addf = (const float*)d_in[6];
    const float* gW0 = (const float*)d_in[7],  *gb0 = (const float*)d_in[8];
    const float* gas0 = (const float*)d_in[9], *gad0 = (const float*)d_in[10];
    const float* gW1 = (const float*)d_in[11], *gb1 = (const float*)d_in[12];
    const float* gas1 = (const float*)d_in[13], *gad1 = (const float*)d_in[14];
    const float* gW2 = (const float*)d_in[15], *gb2 = (const float*)d_in[16];
    const float* gas2 = (const float*)d_in[17], *gad2 = (const float*)d_in[18];
    const float* bn0g = (const float*)d_in[19], *bn0b = (const float*)d_in[20];
    const float* bn0m = (const float*)d_in[21], *bn0v = (const float*)d_in[22];
    const float* bn1g = (const float*)d_in[23], *bn1b = (const float*)d_in[24];
    const float* bn1m = (const float*)d_in[25], *bn1v = (const float*)d_in[26];
    const float* bn2g = (const float*)d_in[27], *bn2b = (const float*)d_in[28];
    const float* bn2m = (const float*)d_in[29], *bn2v = (const float*)d_in[30];
    const float* mW0 = (const float*)d_in[31], *mb0 = (const float*)d_in[32];
    const float* mg0 = (const float*)d_in[33], *mbe0 = (const float*)d_in[34];
    const float* mm0 = (const float*)d_in[35], *mv0 = (const float*)d_in[36];
    const float* mW1 = (const float*)d_in[37], *mb1 = (const float*)d_in[38];
    const float* mg1 = (const float*)d_in[39], *mbe1 = (const float*)d_in[40];
    const float* mm1 = (const float*)d_in[41], *mv1 = (const float*)d_in[42];
    const float* mW2 = (const float*)d_in[43], *mb2 = (const float*)d_in[44];

    // ---- workspace layout ----
    char* p = (char*)d_ws;
    const size_t CMB_BYTES = (size_t)B_GRAPHS * 512 * sizeof(float);   // 8 MB
    float* cmb = (float*)p; p += CMB_BYTES;
    unsigned short* W0t = (unsigned short*)p; p += (size_t)D0 * KP0 * 2;   // 96 KB
    unsigned short* W1t = (unsigned short*)p; p += (size_t)D0 * D0 * 2;    // 512 KB
    unsigned short* W2t = (unsigned short*)p; p += (size_t)HID * D0 * 2;   // 128 KB
    size_t used = (size_t)(p - (char*)d_ws);
    // per-graph: Xb 7680 + B1 40960 + B2 40960 + ES 640 + ED 640 + ALPHA 3200
    const size_t PG = 7680ull + 40960ull + 40960ull + 640ull + 640ull + 3200ull;
    int chunk = B_GRAPHS;
    while (chunk > 4 && used + (size_t)chunk * PG > ws_size) chunk >>= 1;
    if (used + (size_t)chunk * PG > ws_size) {
        write_code_kernel<<<(out_n + 255) / 256, 256, 0, stream>>>(out, out_n, 500000.f);
        return;
    }
    unsigned short* Xb = (unsigned short*)p; p += (size_t)chunk * 7680;
    unsigned short* B1 = (unsigned short*)p; p += (size_t)chunk * 40960;
    unsigned short* B2 = (unsigned short*)p; p += (size_t)chunk * 40960;
    float* ES = (float*)p;    p += (size_t)chunk * 640;
    float* ED = (float*)p;    p += (size_t)chunk * 640;
    float* ALPHA = (float*)p;

    // ---- weight conversion (once) ----
    convw_kernel<<<(D0 * KP0 + 255) / 256, 256, 0, stream>>>(gW0, W0t, F_IN, D0, KP0);
    convw_kernel<<<(D0 * D0 + 255) / 256, 256, 0, stream>>>(gW1, W1t, D0, D0, D0);
    convw_kernel<<<(HID * D0 + 255) / 256, 256, 0, stream>>>(gW2, W2t, D0, HID, D0);

    for (int drug = 0; drug < 2; drug++) {
        const float* x = drug ? x_b : x_a;
        const int* edge = drug ? edge_b : edge_a;
        int colbase = drug ? 256 : 0;

        for (int g0 = 0; g0 < B_GRAPHS; g0 += chunk) {
            int n = chunk * NPG;
            int gy = (n + 63) / 64;
            // layer 0
            convx_kernel<<<(n * KP0 + 255) / 256, 256, 0, stream>>>(
                x + (size_t)g0 * NPG * F_IN, Xb, n);
            gemm_mfma_kernel<<<dim3(D0 / 64, gy), 256, 0, stream>>>(
                Xb, W0t, B1, n, KP0, D0);
            att_logits_kernel<<<(n * 4 + 255) / 256, 256, 0, stream>>>(
                B1, gas0, gad0, ES, ED, n, 4, HID);
            att_alpha_kernel<<<(n * 4 + 255) / 256, 256, 0, stream>>>(
                edge, ES, ED, ALPHA, chunk, g0, 4);
            att_agg_kernel<<<(n * D0 + 255) / 256, 256, 0, stream>>>(
                B1, edge, ALPHA, gb0, bn0g, bn0b, bn0m, bn0v,
                B2, nullptr, chunk, g0, 4, HID, 1);
            // layer 1
            gemm_mfma_kernel<<<dim3(D0 / 64, gy), 256, 0, stream>>>(
                B2, W1t, B1, n, D0, D0);
            att_logits_kernel<<<(n * 4 + 255) / 256, 256, 0, stream>>>(
                B1, gas1, gad1, ES, ED, n, 4, HID);
            att_alpha_kernel<<<(n * 4 + 255) / 256, 256, 0, stream>>>(
                edge, ES, ED, ALPHA, chunk, g0, 4);
            att_agg_kernel<<<(n * D0 + 255) / 256, 256, 0, stream>>>(
                B1, edge, ALPHA, gb1, bn1g, bn1b, bn1m, bn1v,
                B2, nullptr, chunk, g0, 4, HID, 1);
            // layer 2
            gemm_mfma_kernel<<<dim3(HID / 64, gy), 256, 0, stream>>>(
                B2, W2t, B1, n, D0, HID);
            att_logits_kernel<<<(n + 255) / 256, 256, 0, stream>>>(
                B1, gas2, gad2, ES, ED, n, 1, HID);
            att_alpha_kernel<<<(n + 255) / 256, 256, 0, stream>>>(
                edge, ES, ED, ALPHA, chunk, g0, 1);
            att_agg_kernel<<<(n * HID + 255) / 256, 256, 0, stream>>>(
                B1, edge, ALPHA, gb2, bn2g, bn2b, bn2m, bn2v,
                nullptr, (float*)B2, chunk, g0, 1, HID, 0);
            pool_kernel<<<(chunk * 2 * HID + 255) / 256, 256, 0, stream>>>(
                (const float*)B2, cmb, chunk, g0, colbase);
        }
    }
    mlp_kernel<<<B_GRAPHS, 256, 0, stream>>>(
        cmb, addf, mW0, mb0, mg0, mbe0, mm0, mv0,
        mW1, mb1, mg1, mbe1, mm1, mv1, mW2, mb2, out);
}

// Round 9
// 8642.406 us; speedup vs baseline: 7.8558x; 3.4027x over previous
//
#include <hip/hip_runtime.h>
#include <stdint.h>

#define B_GRAPHS 4096
#define NPG 40
#define NTOT (B_GRAPHS * NPG)      // 163840
#define EPG 160
#define ETOT (B_GRAPHS * EPG)      // 655360
#define ESL 200                    // 160 edges + 40 self-loop slots
#define F_IN 78
#define KP0 96                     // F_IN padded to multiple of 32
#define HID 128
#define D0 512
#define CMB 520
#define BN_EPS 1e-5f

typedef short bf16x8 __attribute__((ext_vector_type(8)));
typedef float floatx4 __attribute__((ext_vector_type(4)));

__device__ inline float b2f(unsigned short u) {
    union { float f; uint32_t i; } v; v.i = ((uint32_t)u) << 16; return v.f;
}
__device__ inline unsigned short f2b(float f) {
    union { float f; uint32_t i; } v; v.f = f;
    uint32_t x = v.i;
    return (unsigned short)((x + 0x7fffu + ((x >> 16) & 1u)) >> 16);
}
__device__ inline float lo16(uint32_t u) {
    union { float f; uint32_t i; } v; v.i = u << 16; return v.f;
}
__device__ inline float hi16(uint32_t u) {
    union { float f; uint32_t i; } v; v.i = u & 0xffff0000u; return v.f;
}

__global__ __launch_bounds__(256)
void write_code_kernel(float* __restrict__ out, int n, float S)
{
    int i = blockIdx.x * 256 + threadIdx.x;
    if (i < n) out[i] = (i == 0) ? S : 0.f;
}

// ---------------------------------------------------------------------------
// Weight convert: W [K,N] fp32 -> Wt [N,Kp] bf16 (transposed, zero-padded K)
// ---------------------------------------------------------------------------
__global__ __launch_bounds__(256)
void convw_kernel(const float* __restrict__ W, unsigned short* __restrict__ Wt,
                  int K, int N, int Kp)
{
    int t = blockIdx.x * 256 + threadIdx.x;
    if (t >= N * Kp) return;
    int n = t / Kp, k = t - n * Kp;
    Wt[t] = (k < K) ? f2b(W[(size_t)k * N + n]) : 0;
}

// x convert: X [M,78] fp32 -> Xb [M,96] bf16 zero-padded
__global__ __launch_bounds__(256)
void convx_kernel(const float* __restrict__ X, unsigned short* __restrict__ Xb, int M)
{
    int t = blockIdx.x * 256 + threadIdx.x;
    if (t >= M * KP0) return;
    int r = t / KP0, k = t - r * KP0;
    Xb[t] = (k < F_IN) ? f2b(X[(size_t)r * F_IN + k]) : 0;
}

// ---------------------------------------------------------------------------
// MFMA GEMM: C[M,N] = A[M,K] @ Bt[N,K]^T, bf16 in/out, fp32 accum.
// 64x64 tile, BK=32, 4 waves. K % 32 == 0. M guarded.  [layouts HW-verified]
// ---------------------------------------------------------------------------
__global__ __launch_bounds__(256)
void gemm_mfma_kernel(const unsigned short* __restrict__ A,
                      const unsigned short* __restrict__ Bt,
                      unsigned short* __restrict__ C,
                      int M, int K, int N)
{
    __shared__ __align__(16) unsigned short As[64 * 32];
    __shared__ __align__(16) unsigned short Bs[64 * 32];
    const int tid  = threadIdx.x;
    const int lane = tid & 63, wave = tid >> 6;
    const int quad = lane >> 4, l16 = lane & 15;
    const int row0 = blockIdx.y * 64, col0 = blockIdx.x * 64;

    floatx4 acc0 = {0.f,0.f,0.f,0.f}, acc1 = {0.f,0.f,0.f,0.f};
    floatx4 acc2 = {0.f,0.f,0.f,0.f}, acc3 = {0.f,0.f,0.f,0.f};

    const int r = tid >> 2, kk = (tid & 3) * 8;
    for (int k0 = 0; k0 < K; k0 += 32) {
        if (row0 + r < M) {
            uint4 v = *(const uint4*)(A + (size_t)(row0 + r) * K + k0 + kk);
            *(uint4*)(&As[r * 32 + kk]) = v;
        } else {
            *(uint4*)(&As[r * 32 + kk]) = make_uint4(0, 0, 0, 0);
        }
        {
            uint4 v = *(const uint4*)(Bt + (size_t)(col0 + r) * K + k0 + kk);
            *(uint4*)(&Bs[r * 32 + kk]) = v;
        }
        __syncthreads();

        bf16x8 a, b0, b1, b2v, b3;
        __builtin_memcpy(&a,   &As[(wave * 16 + l16) * 32 + quad * 8], 16);
        __builtin_memcpy(&b0,  &Bs[( 0 + l16) * 32 + quad * 8], 16);
        __builtin_memcpy(&b1,  &Bs[(16 + l16) * 32 + quad * 8], 16);
        __builtin_memcpy(&b2v, &Bs[(32 + l16) * 32 + quad * 8], 16);
        __builtin_memcpy(&b3,  &Bs[(48 + l16) * 32 + quad * 8], 16);
        acc0 = __builtin_amdgcn_mfma_f32_16x16x32_bf16(a, b0,  acc0, 0, 0, 0);
        acc1 = __builtin_amdgcn_mfma_f32_16x16x32_bf16(a, b1,  acc1, 0, 0, 0);
        acc2 = __builtin_amdgcn_mfma_f32_16x16x32_bf16(a, b2v, acc2, 0, 0, 0);
        acc3 = __builtin_amdgcn_mfma_f32_16x16x32_bf16(a, b3,  acc3, 0, 0, 0);
        __syncthreads();
    }
    const int orow = row0 + wave * 16 + quad * 4;
    #pragma unroll
    for (int rr = 0; rr < 4; rr++) {
        if (orow + rr >= M) break;
        size_t base = (size_t)(orow + rr) * N + col0 + l16;
        C[base +  0] = f2b(acc0[rr]);
        C[base + 16] = f2b(acc1[rr]);
        C[base + 32] = f2b(acc2[rr]);
        C[base + 48] = f2b(acc3[rr]);
    }
}

// ---------------------------------------------------------------------------
// Fused GAT (4 heads x 128, concat 512) + bias + BN + ReLU. In-place on H.
// One block per graph. LDS ~55 KB (2-head groups).
// ---------------------------------------------------------------------------
__global__ __launch_bounds__(256)
void gat4_fused_kernel(unsigned short* __restrict__ H,     // [chunk*40, 512]
                       const int* __restrict__ edge,
                       const float* __restrict__ avs, const float* __restrict__ avd,
                       const float* __restrict__ bias,
                       const float* __restrict__ bng, const float* __restrict__ bnb,
                       const float* __restrict__ bnm, const float* __restrict__ bnv,
                       int g0)
{
    __shared__ __align__(16) unsigned short h[NPG * D0];   // 40 KB
    __shared__ float A2[2][NPG * NPG];                     // 12.8 KB
    __shared__ float es[NPG * 4], ed[NPG * 4];
    __shared__ short2 eloc[ESL];
    const int tid = threadIdx.x;
    const int gg = g0 + blockIdx.x;
    unsigned short* Hg = H + (size_t)blockIdx.x * NPG * D0;

    {   // load node features
        const uint4* s = (const uint4*)Hg;
        uint4* d = (uint4*)h;
        for (int i = tid; i < NPG * D0 / 8; i += 256) d[i] = s[i];
    }
    for (int i = tid; i < ESL; i += 256) {
        if (i < EPG) {
            int s  = edge[(size_t)gg * EPG + i] - gg * NPG;
            int dd = edge[(size_t)ETOT + (size_t)gg * EPG + i] - gg * NPG;
            eloc[i] = make_short2((short)s, (short)dd);
        } else {
            short v = (short)(i - EPG);
            eloc[i] = make_short2(v, v);
        }
    }
    __syncthreads();
    // logits per (node, head, src/dst): 320 units
    for (int t = tid; t < NPG * 8; t += 256) {
        int node = t >> 3, hd = (t >> 1) & 3, which = t & 1;
        const float* av = which ? avd : avs;
        const unsigned short* hr = &h[node * D0 + hd * HID];
        float acc = 0.f;
        #pragma unroll 4
        for (int c = 0; c < HID; c++) acc += b2f(hr[c]) * av[hd * HID + c];
        if (which) ed[node * 4 + hd] = acc; else es[node * 4 + hd] = acc;
    }
    __syncthreads();

    for (int grp = 0; grp < 2; grp++) {
        for (int i = tid; i < 2 * NPG * NPG; i += 256) (&A2[0][0])[i] = 0.f;
        __syncthreads();
        if (tid < 2 * NPG) {                 // (dst, head-in-group)
            int dn = tid >> 1, hh = tid & 1, hd = grp * 2 + hh;
            float edv = ed[dn * 4 + hd];
            float m = -1e30f;
            for (int e = 0; e < ESL; e++) {
                short2 sd = eloc[e];
                if (sd.y != dn) continue;
                float v = es[sd.x * 4 + hd] + edv;
                v = v > 0.f ? v : 0.2f * v;
                m = fmaxf(m, v);
            }
            float den = 0.f;
            float* Ar = &A2[hh][dn * NPG];
            for (int e = 0; e < ESL; e++) {
                short2 sd = eloc[e];
                if (sd.y != dn) continue;
                float v = es[sd.x * 4 + hd] + edv;
                v = v > 0.f ? v : 0.2f * v;
                float ex = __expf(v - m);
                Ar[sd.x] += ex; den += ex;
            }
            float inv = 1.f / den;
            for (int s = 0; s < NPG; s++) Ar[s] *= inv;
        }
        __syncthreads();
        // aggregate this group's 256 channels: units (dn, octet) = 40*32
        for (int u = tid; u < NPG * 32; u += 256) {
            int dn = u >> 5, oc = u & 31;
            int hh = oc >> 4;                        // head within group
            int gch = grp * 256 + oc * 8;            // global channel base
            const float* Ar = &A2[hh][dn * NPG];
            float a0=0,a1=0,a2=0,a3=0,a4=0,a5=0,a6=0,a7=0;
            for (int s = 0; s < NPG; s++) {
                float a = Ar[s];
                uint4 pk = *(const uint4*)&h[s * D0 + gch];
                a0 += a * lo16(pk.x); a1 += a * hi16(pk.x);
                a2 += a * lo16(pk.y); a3 += a * hi16(pk.y);
                a4 += a * lo16(pk.z); a5 += a * hi16(pk.z);
                a6 += a * lo16(pk.w); a7 += a * hi16(pk.w);
            }
            float vr[8] = {a0,a1,a2,a3,a4,a5,a6,a7};
            uint32_t pkout[4];
            #pragma unroll
            for (int j = 0; j < 4; j++) {
                int c0 = gch + 2 * j, c1 = c0 + 1;
                float o0 = vr[2*j]   + bias[c0];
                float o1 = vr[2*j+1] + bias[c1];
                o0 = (o0 - bnm[c0]) * rsqrtf(bnv[c0] + BN_EPS) * bng[c0] + bnb[c0];
                o1 = (o1 - bnm[c1]) * rsqrtf(bnv[c1] + BN_EPS) * bng[c1] + bnb[c1];
                o0 = fmaxf(o0, 0.f); o1 = fmaxf(o1, 0.f);
                pkout[j] = (uint32_t)f2b(o0) | ((uint32_t)f2b(o1) << 16);
            }
            *(uint4*)&Hg[(size_t)dn * D0 + gch] =
                make_uint4(pkout[0], pkout[1], pkout[2], pkout[3]);
        }
        __syncthreads();
    }
}

// ---------------------------------------------------------------------------
// Fused GAT (1 head, 128) + bias + BN (no relu) + mean/max pool -> cmb
// ---------------------------------------------------------------------------
__global__ __launch_bounds__(256)
void gat1_pool_fused_kernel(const unsigned short* __restrict__ H,  // [chunk*40,128]
                            const int* __restrict__ edge,
                            const float* __restrict__ avs, const float* __restrict__ avd,
                            const float* __restrict__ bias,
                            const float* __restrict__ bng, const float* __restrict__ bnb,
                            const float* __restrict__ bnm, const float* __restrict__ bnv,
                            float* __restrict__ cmb, int colbase, int g0)
{
    __shared__ __align__(16) unsigned short h[NPG * HID];  // 10 KB
    __shared__ float A[NPG * NPG];                         // 6.4 KB
    __shared__ float es[NPG], ed[NPG];
    __shared__ short2 eloc[ESL];
    __shared__ float ob[NPG * HID];                        // 20.5 KB
    const int tid = threadIdx.x;
    const int gg = g0 + blockIdx.x;
    const unsigned short* Hg = H + (size_t)blockIdx.x * NPG * HID;

    {
        const uint4* s = (const uint4*)Hg;
        uint4* d = (uint4*)h;
        for (int i = tid; i < NPG * HID / 8; i += 256) d[i] = s[i];
    }
    for (int i = tid; i < ESL; i += 256) {
        if (i < EPG) {
            int s  = edge[(size_t)gg * EPG + i] - gg * NPG;
            int dd = edge[(size_t)ETOT + (size_t)gg * EPG + i] - gg * NPG;
            eloc[i] = make_short2((short)s, (short)dd);
        } else {
            short v = (short)(i - EPG);
            eloc[i] = make_short2(v, v);
        }
    }
    for (int i = tid; i < NPG * NPG; i += 256) A[i] = 0.f;
    __syncthreads();
    for (int t = tid; t < NPG * 2; t += 256) {
        int node = t >> 1, which = t & 1;
        const float* av = which ? avd : avs;
        const unsigned short* hr = &h[node * HID];
        float acc = 0.f;
        #pragma unroll 4
        for (int c = 0; c < HID; c++) acc += b2f(hr[c]) * av[c];
        if (which) ed[node] = acc; else es[node] = acc;
    }
    __syncthreads();
    if (tid < NPG) {
        int dn = tid;
        float edv = ed[dn];
        float m = -1e30f;
        for (int e = 0; e < ESL; e++) {
            short2 sd = eloc[e];
            if (sd.y != dn) continue;
            float v = es[sd.x] + edv;
            v = v > 0.f ? v : 0.2f * v;
            m = fmaxf(m, v);
        }
        float den = 0.f;
        float* Ar = &A[dn * NPG];
        for (int e = 0; e < ESL; e++) {
            short2 sd = eloc[e];
            if (sd.y != dn) continue;
            float v = es[sd.x] + edv;
            v = v > 0.f ? v : 0.2f * v;
            float ex = __expf(v - m);
            Ar[sd.x] += ex; den += ex;
        }
        float inv = 1.f / den;
        for (int s = 0; s < NPG; s++) Ar[s] *= inv;
    }
    __syncthreads();
    // aggregate: units (dn, octet) = 40*16
    for (int u = tid; u < NPG * 16; u += 256) {
        int dn = u >> 4, oc = u & 15;
        int ch = oc * 8;
        const float* Ar = &A[dn * NPG];
        float a0=0,a1=0,a2=0,a3=0,a4=0,a5=0,a6=0,a7=0;
        for (int s = 0; s < NPG; s++) {
            float a = Ar[s];
            uint4 pk = *(const uint4*)&h[s * HID + ch];
            a0 += a * lo16(pk.x); a1 += a * hi16(pk.x);
            a2 += a * lo16(pk.y); a3 += a * hi16(pk.y);
            a4 += a * lo16(pk.z); a5 += a * hi16(pk.z);
            a6 += a * lo16(pk.w); a7 += a * hi16(pk.w);
        }
        float vr[8] = {a0,a1,a2,a3,a4,a5,a6,a7};
        #pragma unroll
        for (int j = 0; j < 8; j++) {
            int c = ch + j;
            float o = vr[j] + bias[c];
            o = (o - bnm[c]) * rsqrtf(bnv[c] + BN_EPS) * bng[c] + bnb[c];
            ob[dn * HID + c] = o;     // no relu
        }
    }
    __syncthreads();
    {   // pool: 256 threads = 128 ch x {mean,max}
        int c = tid & 127, which = tid >> 7;
        const float* bp = &ob[c];
        if (!which) {
            float s = 0.f;
            for (int i = 0; i < NPG; i++) s += bp[i * HID];
            cmb[(size_t)gg * 512 + colbase + c] = s * (1.f / NPG);
        } else {
            float m = -1e30f;
            for (int i = 0; i < NPG; i++) m = fmaxf(m, bp[i * HID]);
            cmb[(size_t)gg * 512 + colbase + HID + c] = m;
        }
    }
}

// ---------------------------------------------------------------------------
// Final MLP: [520] -> 256 (BN,ReLU) -> 128 (BN,ReLU) -> 1 (sigmoid), fp32
// ---------------------------------------------------------------------------
__global__ __launch_bounds__(256)
void mlp_kernel(const float* __restrict__ cmb, const float* __restrict__ addf,
                const float* __restrict__ W0, const float* __restrict__ b0,
                const float* __restrict__ g0v, const float* __restrict__ be0,
                const float* __restrict__ m0, const float* __restrict__ v0,
                const float* __restrict__ W1, const float* __restrict__ b1,
                const float* __restrict__ g1v, const float* __restrict__ be1,
                const float* __restrict__ m1, const float* __restrict__ v1,
                const float* __restrict__ W2, const float* __restrict__ b2,
                float* __restrict__ out)
{
    __shared__ float c[CMB];
    __shared__ float h1[256];
    __shared__ float h2[128];
    const int g = blockIdx.x, tid = threadIdx.x;
    for (int i = tid; i < 512; i += 256) c[i] = cmb[(size_t)g * 512 + i];
    if (tid < 8) c[512 + tid] = addf[g * 8 + tid];
    __syncthreads();
    {
        int j = tid;
        float acc = b0[j];
        for (int k = 0; k < CMB; k++) acc += c[k] * W0[k * 256 + j];
        acc = (acc - m0[j]) * rsqrtf(v0[j] + BN_EPS) * g0v[j] + be0[j];
        h1[j] = fmaxf(acc, 0.f);
    }
    __syncthreads();
    if (tid < 128) {
        int j = tid;
        float acc = b1[j];
        for (int k = 0; k < 256; k++) acc += h1[k] * W1[k * 128 + j];
        acc = (acc - m1[j]) * rsqrtf(v1[j] + BN_EPS) * g1v[j] + be1[j];
        h2[j] = fmaxf(acc, 0.f);
    }
    __syncthreads();
    if (tid == 0) {
        float acc = b2[0];
        for (int k = 0; k < 128; k++) acc += h2[k] * W2[k];
        out[g] = 1.f / (1.f + __expf(-acc));
    }
}

// ---------------------------------------------------------------------------
extern "C" void kernel_launch(void* const* d_in, const int* in_sizes, int n_in,
                              void* d_out, int out_size, void* d_ws, size_t ws_size,
                              hipStream_t stream)
{
    float* out = (float*)d_out;
    int out_n = out_size < 4096 ? out_size : 4096;

    const float* x_a  = (const float*)d_in[0];
    const int*   edge_a = (const int*)d_in[1];
    const float* x_b  = (const float*)d_in[3];
    const int*   edge_b = (const int*)d_in[4];
    const float* addf = (const float*)d_in[6];
    const float* gW0 = (const float*)d_in[7],  *gb0 = (const float*)d_in[8];
    const float* gas0 = (const float*)d_in[9], *gad0 = (const float*)d_in[10];
    const float* gW1 = (const float*)d_in[11], *gb1 = (const float*)d_in[12];
    const float* gas1 = (const float*)d_in[13], *gad1 = (const float*)d_in[14];
    const float* gW2 = (const float*)d_in[15], *gb2 = (const float*)d_in[16];
    const float* gas2 = (const float*)d_in[17], *gad2 = (const float*)d_in[18];
    const float* bn0g = (const float*)d_in[19], *bn0b = (const float*)d_in[20];
    const float* bn0m = (const float*)d_in[21], *bn0v = (const float*)d_in[22];
    const float* bn1g = (const float*)d_in[23], *bn1b = (const float*)d_in[24];
    const float* bn1m = (const float*)d_in[25], *bn1v = (const float*)d_in[26];
    const float* bn2g = (const float*)d_in[27], *bn2b = (const float*)d_in[28];
    const float* bn2m = (const float*)d_in[29], *bn2v = (const float*)d_in[30];
    const float* mW0 = (const float*)d_in[31], *mb0 = (const float*)d_in[32];
    const float* mg0 = (const float*)d_in[33], *mbe0 = (const float*)d_in[34];
    const float* mm0 = (const float*)d_in[35], *mv0 = (const float*)d_in[36];
    const float* mW1 = (const float*)d_in[37], *mb1 = (const float*)d_in[38];
    const float* mg1 = (const float*)d_in[39], *mbe1 = (const float*)d_in[40];
    const float* mm1 = (const float*)d_in[41], *mv1 = (const float*)d_in[42];
    const float* mW2 = (const float*)d_in[43], *mb2 = (const float*)d_in[44];

    // ---- workspace layout ----
    char* p = (char*)d_ws;
    const size_t CMB_BYTES = (size_t)B_GRAPHS * 512 * sizeof(float);   // 8 MB
    float* cmb = (float*)p; p += CMB_BYTES;
    unsigned short* W0t = (unsigned short*)p; p += (size_t)D0 * KP0 * 2;
    unsigned short* W1t = (unsigned short*)p; p += (size_t)D0 * D0 * 2;
    unsigned short* W2t = (unsigned short*)p; p += (size_t)HID * D0 * 2;
    size_t used = (size_t)(p - (char*)d_ws);
    // per-graph: Xb 7680 + B1 40960 + B2 40960
    const size_t PG = 7680ull + 40960ull + 40960ull;
    int chunk = B_GRAPHS;
    while (chunk > 4 && used + (size_t)chunk * PG > ws_size) chunk >>= 1;
    if (used + (size_t)chunk * PG > ws_size) {
        write_code_kernel<<<(out_n + 255) / 256, 256, 0, stream>>>(out, out_n, 500000.f);
        return;
    }
    unsigned short* Xb = (unsigned short*)p; p += (size_t)chunk * 7680;
    unsigned short* B1 = (unsigned short*)p; p += (size_t)chunk * 40960;
    unsigned short* B2 = (unsigned short*)p;

    // ---- weight conversion (once) ----
    convw_kernel<<<(D0 * KP0 + 255) / 256, 256, 0, stream>>>(gW0, W0t, F_IN, D0, KP0);
    convw_kernel<<<(D0 * D0 + 255) / 256, 256, 0, stream>>>(gW1, W1t, D0, D0, D0);
    convw_kernel<<<(HID * D0 + 255) / 256, 256, 0, stream>>>(gW2, W2t, D0, HID, D0);

    for (int drug = 0; drug < 2; drug++) {
        const float* x = drug ? x_b : x_a;
        const int* edge = drug ? edge_b : edge_a;
        int colbase = drug ? 256 : 0;

        for (int g0 = 0; g0 < B_GRAPHS; g0 += chunk) {
            int n = chunk * NPG;
            int gy = (n + 63) / 64;
            // layer 0
            convx_kernel<<<(n * KP0 + 255) / 256, 256, 0, stream>>>(
                x + (size_t)g0 * NPG * F_IN, Xb, n);
            gemm_mfma_kernel<<<dim3(D0 / 64, gy), 256, 0, stream>>>(
                Xb, W0t, B1, n, KP0, D0);
            gat4_fused_kernel<<<chunk, 256, 0, stream>>>(
                B1, edge, gas0, gad0, gb0, bn0g, bn0b, bn0m, bn0v, g0);
            // layer 1
            gemm_mfma_kernel<<<dim3(D0 / 64, gy), 256, 0, stream>>>(
                B1, W1t, B2, n, D0, D0);
            gat4_fused_kernel<<<chunk, 256, 0, stream>>>(
                B2, edge, gas1, gad1, gb1, bn1g, bn1b, bn1m, bn1v, g0);
            // layer 2
            gemm_mfma_kernel<<<dim3(HID / 64, gy), 256, 0, stream>>>(
                B2, W2t, B1, n, D0, HID);
            gat1_pool_fused_kernel<<<chunk, 256, 0, stream>>>(
                B1, edge, gas2, gad2, gb2, bn2g, bn2b, bn2m, bn2v,
                cmb, colbase, g0);
        }
    }
    mlp_kernel<<<B_GRAPHS, 256, 0, stream>>>(
        cmb, addf, mW0, mb0, mg0, mbe0, mm0, mv0,
        mW1, mb1, mg1, mbe1, mm1, mv1, mW2, mb2, out);
}

// Round 10
// 4067.087 us; speedup vs baseline: 16.6932x; 2.1250x over previous
//
#include <hip/hip_runtime.h>
#include <stdint.h>

#define B_GRAPHS 4096
#define NPG 40
#define NTOT (B_GRAPHS * NPG)      // 163840
#define EPG 160
#define ETOT (B_GRAPHS * EPG)      // 655360
#define ESL 200                    // 160 edges + 40 self-loop slots
#define F_IN 78
#define KP0 96                     // F_IN padded to multiple of 32
#define HID 128
#define D0 512
#define CMB 520
#define BN_EPS 1e-5f

typedef short bf16x8 __attribute__((ext_vector_type(8)));
typedef float floatx4 __attribute__((ext_vector_type(4)));

__device__ inline float b2f(unsigned short u) {
    union { float f; uint32_t i; } v; v.i = ((uint32_t)u) << 16; return v.f;
}
__device__ inline unsigned short f2b(float f) {
    union { float f; uint32_t i; } v; v.f = f;
    uint32_t x = v.i;
    return (unsigned short)((x + 0x7fffu + ((x >> 16) & 1u)) >> 16);
}
__device__ inline float lo16(uint32_t u) {
    union { float f; uint32_t i; } v; v.i = u << 16; return v.f;
}
__device__ inline float hi16(uint32_t u) {
    union { float f; uint32_t i; } v; v.i = u & 0xffff0000u; return v.f;
}

__global__ __launch_bounds__(256)
void write_code_kernel(float* __restrict__ out, int n, float S)
{
    int i = blockIdx.x * 256 + threadIdx.x;
    if (i < n) out[i] = (i == 0) ? S : 0.f;
}

// ---------------------------------------------------------------------------
// Weight convert: W [K,N] fp32 -> Wt [N,Kp] bf16 (transposed, zero-padded K)
// ---------------------------------------------------------------------------
__global__ __launch_bounds__(256)
void convw_kernel(const float* __restrict__ W, unsigned short* __restrict__ Wt,
                  int K, int N, int Kp)
{
    int t = blockIdx.x * 256 + threadIdx.x;
    if (t >= N * Kp) return;
    int n = t / Kp, k = t - n * Kp;
    Wt[t] = (k < K) ? f2b(W[(size_t)k * N + n]) : 0;
}

// x convert: X [M,78] fp32 -> Xb [M,96] bf16 zero-padded
__global__ __launch_bounds__(256)
void convx_kernel(const float* __restrict__ X, unsigned short* __restrict__ Xb, int M)
{
    int t = blockIdx.x * 256 + threadIdx.x;
    if (t >= M * KP0) return;
    int r = t / KP0, k = t - r * KP0;
    Xb[t] = (k < F_IN) ? f2b(X[(size_t)r * F_IN + k]) : 0;
}

// ---------------------------------------------------------------------------
// MFMA GEMM: C[M,N] = A[M,K] @ Bt[N,K]^T, bf16 in/out, fp32 accum.
// 64x64 tile, BK=32, 4 waves. K % 32 == 0. M guarded.  [layouts HW-verified]
// ---------------------------------------------------------------------------
__global__ __launch_bounds__(256)
void gemm_mfma_kernel(const unsigned short* __restrict__ A,
                      const unsigned short* __restrict__ Bt,
                      unsigned short* __restrict__ C,
                      int M, int K, int N)
{
    __shared__ __align__(16) unsigned short As[64 * 32];
    __shared__ __align__(16) unsigned short Bs[64 * 32];
    const int tid  = threadIdx.x;
    const int lane = tid & 63, wave = tid >> 6;
    const int quad = lane >> 4, l16 = lane & 15;
    const int row0 = blockIdx.y * 64, col0 = blockIdx.x * 64;

    floatx4 acc0 = {0.f,0.f,0.f,0.f}, acc1 = {0.f,0.f,0.f,0.f};
    floatx4 acc2 = {0.f,0.f,0.f,0.f}, acc3 = {0.f,0.f,0.f,0.f};

    const int r = tid >> 2, kk = (tid & 3) * 8;
    for (int k0 = 0; k0 < K; k0 += 32) {
        if (row0 + r < M) {
            uint4 v = *(const uint4*)(A + (size_t)(row0 + r) * K + k0 + kk);
            *(uint4*)(&As[r * 32 + kk]) = v;
        } else {
            *(uint4*)(&As[r * 32 + kk]) = make_uint4(0, 0, 0, 0);
        }
        {
            uint4 v = *(const uint4*)(Bt + (size_t)(col0 + r) * K + k0 + kk);
            *(uint4*)(&Bs[r * 32 + kk]) = v;
        }
        __syncthreads();

        bf16x8 a, b0, b1, b2v, b3;
        __builtin_memcpy(&a,   &As[(wave * 16 + l16) * 32 + quad * 8], 16);
        __builtin_memcpy(&b0,  &Bs[( 0 + l16) * 32 + quad * 8], 16);
        __builtin_memcpy(&b1,  &Bs[(16 + l16) * 32 + quad * 8], 16);
        __builtin_memcpy(&b2v, &Bs[(32 + l16) * 32 + quad * 8], 16);
        __builtin_memcpy(&b3,  &Bs[(48 + l16) * 32 + quad * 8], 16);
        acc0 = __builtin_amdgcn_mfma_f32_16x16x32_bf16(a, b0,  acc0, 0, 0, 0);
        acc1 = __builtin_amdgcn_mfma_f32_16x16x32_bf16(a, b1,  acc1, 0, 0, 0);
        acc2 = __builtin_amdgcn_mfma_f32_16x16x32_bf16(a, b2v, acc2, 0, 0, 0);
        acc3 = __builtin_amdgcn_mfma_f32_16x16x32_bf16(a, b3,  acc3, 0, 0, 0);
        __syncthreads();
    }
    const int orow = row0 + wave * 16 + quad * 4;
    #pragma unroll
    for (int rr = 0; rr < 4; rr++) {
        if (orow + rr >= M) break;
        size_t base = (size_t)(orow + rr) * N + col0 + l16;
        C[base +  0] = f2b(acc0[rr]);
        C[base + 16] = f2b(acc1[rr]);
        C[base + 32] = f2b(acc2[rr]);
        C[base + 48] = f2b(acc3[rr]);
    }
}

// ---------------------------------------------------------------------------
// Fused GAT (4 heads x 128, concat 512) + bias + BN + ReLU. In-place on H.
// One block/graph. h stored XOR-swizzled: chunk c8 of row s at (c8^(s&7))*8.
// Alpha stored transposed A2t[hd][s*40+dn] (conflict-free lane-consecutive dn).
// Aggregation units u = oc*40+dn -> h reads broadcast across the wave.
// ---------------------------------------------------------------------------
__global__ __launch_bounds__(256)
void gat4_fused_kernel(unsigned short* __restrict__ H,     // [chunk*40, 512]
                       const int* __restrict__ edge,
                       const float* __restrict__ avs, const float* __restrict__ avd,
                       const float* __restrict__ bias,
                       const float* __restrict__ bng, const float* __restrict__ bnb,
                       const float* __restrict__ bnm, const float* __restrict__ bnv,
                       int g0)
{
    __shared__ __align__(16) unsigned short h[NPG * D0];   // 40 KB (swizzled)
    __shared__ float A2t[4][NPG * NPG];                    // 25.6 KB [hd][s*40+dn]
    __shared__ float es[NPG * 4], ed[NPG * 4];
    __shared__ short2 eloc[ESL];
    const int tid = threadIdx.x;
    const int gg = g0 + blockIdx.x;
    unsigned short* Hg = H + (size_t)blockIdx.x * NPG * D0;

    // stage node features with XOR swizzle
    for (int i = tid; i < NPG * 64; i += 256) {
        int s = i >> 6, c8 = i & 63;
        uint4 v = *(const uint4*)(Hg + (size_t)s * D0 + c8 * 8);
        *(uint4*)(&h[s * D0 + ((c8 ^ (s & 7)) * 8)]) = v;
    }
    for (int i = tid; i < ESL; i += 256) {
        if (i < EPG) {
            int s  = edge[(size_t)gg * EPG + i] - gg * NPG;
            int dd = edge[(size_t)ETOT + (size_t)gg * EPG + i] - gg * NPG;
            eloc[i] = make_short2((short)s, (short)dd);
        } else {
            short v = (short)(i - EPG);
            eloc[i] = make_short2(v, v);
        }
    }
    for (int i = tid; i < 4 * NPG * NPG; i += 256) (&A2t[0][0])[i] = 0.f;
    __syncthreads();

    // logits: 320 units (node, hd, which), vectorized 8ch reads via swizzle
    for (int t = tid; t < NPG * 8; t += 256) {
        int node = t >> 3, hd = (t >> 1) & 3, which = t & 1;
        const float* av = which ? avd : avs;
        float acc = 0.f;
        #pragma unroll
        for (int j = 0; j < 16; j++) {
            int chunk = hd * 16 + j;
            uint4 pk = *(const uint4*)&h[node * D0 + ((chunk ^ (node & 7)) * 8)];
            const float* a = &av[hd * HID + j * 8];
            acc += lo16(pk.x) * a[0] + hi16(pk.x) * a[1]
                 + lo16(pk.y) * a[2] + hi16(pk.y) * a[3]
                 + lo16(pk.z) * a[4] + hi16(pk.z) * a[5]
                 + lo16(pk.w) * a[6] + hi16(pk.w) * a[7];
        }
        if (which) ed[node * 4 + hd] = acc; else es[node * 4 + hd] = acc;
    }
    __syncthreads();

    // softmax: 160 threads (dn, hd) -> A2t[hd][s*40+dn]
    if (tid < NPG * 4) {
        int dn = tid >> 2, hd = tid & 3;
        float edv = ed[dn * 4 + hd];
        float m = -1e30f;
        for (int e = 0; e < ESL; e++) {
            short2 sd = eloc[e];
            if (sd.y != dn) continue;
            float v = es[sd.x * 4 + hd] + edv;
            v = v > 0.f ? v : 0.2f * v;
            m = fmaxf(m, v);
        }
        float den = 0.f;
        float* Ac = &A2t[hd][dn];            // column dn, stride 40
        for (int e = 0; e < ESL; e++) {
            short2 sd = eloc[e];
            if (sd.y != dn) continue;
            float v = es[sd.x * 4 + hd] + edv;
            v = v > 0.f ? v : 0.2f * v;
            float ex = __expf(v - m);
            Ac[sd.x * NPG] += ex; den += ex;
        }
        float inv = 1.f / den;
        for (int s = 0; s < NPG; s++) Ac[s * NPG] *= inv;
    }
    __syncthreads();

    // aggregation: units u = oc*40 + dn (oc = channel octet 0..63)
    for (int u = tid; u < 64 * NPG; u += 256) {
        int oc = u / NPG, dn = u - oc * NPG;
        int hd = oc >> 4;
        const float* At = A2t[hd];
        float a0=0,a1=0,a2=0,a3=0,a4=0,a5=0,a6=0,a7=0;
        for (int s = 0; s < NPG; s++) {
            float a = At[s * NPG + dn];                       // lane-consecutive
            uint4 pk = *(const uint4*)&h[s * D0 + ((oc ^ (s & 7)) * 8)]; // bcast
            a0 += a * lo16(pk.x); a1 += a * hi16(pk.x);
            a2 += a * lo16(pk.y); a3 += a * hi16(pk.y);
            a4 += a * lo16(pk.z); a5 += a * hi16(pk.z);
            a6 += a * lo16(pk.w); a7 += a * hi16(pk.w);
        }
        float vr[8] = {a0,a1,a2,a3,a4,a5,a6,a7};
        int gch = oc * 8;
        uint32_t pkout[4];
        #pragma unroll
        for (int j = 0; j < 4; j++) {
            int c0 = gch + 2 * j, c1 = c0 + 1;
            float o0 = vr[2*j]   + bias[c0];
            float o1 = vr[2*j+1] + bias[c1];
            o0 = (o0 - bnm[c0]) * rsqrtf(bnv[c0] + BN_EPS) * bng[c0] + bnb[c0];
            o1 = (o1 - bnm[c1]) * rsqrtf(bnv[c1] + BN_EPS) * bng[c1] + bnb[c1];
            o0 = fmaxf(o0, 0.f); o1 = fmaxf(o1, 0.f);
            pkout[j] = (uint32_t)f2b(o0) | ((uint32_t)f2b(o1) << 16);
        }
        *(uint4*)&Hg[(size_t)dn * D0 + gch] =
            make_uint4(pkout[0], pkout[1], pkout[2], pkout[3]);
    }
}

// ---------------------------------------------------------------------------
// Fused GAT (1 head, 128) + bias + BN (no relu) + mean/max pool -> cmb
// Same swizzle/transpose scheme; ob padded to stride 129 (conflict-free).
// ---------------------------------------------------------------------------
__global__ __launch_bounds__(256)
void gat1_pool_fused_kernel(const unsigned short* __restrict__ H,  // [chunk*40,128]
                            const int* __restrict__ edge,
                            const float* __restrict__ avs, const float* __restrict__ avd,
                            const float* __restrict__ bias,
                            const float* __restrict__ bng, const float* __restrict__ bnb,
                            const float* __restrict__ bnm, const float* __restrict__ bnv,
                            float* __restrict__ cmb, int colbase, int g0)
{
    __shared__ __align__(16) unsigned short h[NPG * HID];  // 10 KB (swizzled)
    __shared__ float At[NPG * NPG];                        // [s*40+dn] 6.4 KB
    __shared__ float es[NPG], ed[NPG];
    __shared__ short2 eloc[ESL];
    __shared__ float ob[NPG * 129];                        // 20.6 KB, pad 129
    const int tid = threadIdx.x;
    const int gg = g0 + blockIdx.x;
    const unsigned short* Hg = H + (size_t)blockIdx.x * NPG * HID;

    for (int i = tid; i < NPG * 16; i += 256) {
        int s = i >> 4, c8 = i & 15;
        uint4 v = *(const uint4*)(Hg + (size_t)s * HID + c8 * 8);
        *(uint4*)(&h[s * HID + ((c8 ^ (s & 7)) * 8)]) = v;
    }
    for (int i = tid; i < ESL; i += 256) {
        if (i < EPG) {
            int s  = edge[(size_t)gg * EPG + i] - gg * NPG;
            int dd = edge[(size_t)ETOT + (size_t)gg * EPG + i] - gg * NPG;
            eloc[i] = make_short2((short)s, (short)dd);
        } else {
            short v = (short)(i - EPG);
            eloc[i] = make_short2(v, v);
        }
    }
    for (int i = tid; i < NPG * NPG; i += 256) At[i] = 0.f;
    __syncthreads();

    for (int t = tid; t < NPG * 2; t += 256) {
        int node = t >> 1, which = t & 1;
        const float* av = which ? avd : avs;
        float acc = 0.f;
        #pragma unroll
        for (int j = 0; j < 16; j++) {
            uint4 pk = *(const uint4*)&h[node * HID + ((j ^ (node & 7)) * 8)];
            const float* a = &av[j * 8];
            acc += lo16(pk.x) * a[0] + hi16(pk.x) * a[1]
                 + lo16(pk.y) * a[2] + hi16(pk.y) * a[3]
                 + lo16(pk.z) * a[4] + hi16(pk.z) * a[5]
                 + lo16(pk.w) * a[6] + hi16(pk.w) * a[7];
        }
        if (which) ed[node] = acc; else es[node] = acc;
    }
    __syncthreads();
    if (tid < NPG) {
        int dn = tid;
        float edv = ed[dn];
        float m = -1e30f;
        for (int e = 0; e < ESL; e++) {
            short2 sd = eloc[e];
            if (sd.y != dn) continue;
            float v = es[sd.x] + edv;
            v = v > 0.f ? v : 0.2f * v;
            m = fmaxf(m, v);
        }
        float den = 0.f;
        float* Ac = &At[dn];
        for (int e = 0; e < ESL; e++) {
            short2 sd = eloc[e];
            if (sd.y != dn) continue;
            float v = es[sd.x] + edv;
            v = v > 0.f ? v : 0.2f * v;
            float ex = __expf(v - m);
            Ac[sd.x * NPG] += ex; den += ex;
        }
        float inv = 1.f / den;
        for (int s = 0; s < NPG; s++) Ac[s * NPG] *= inv;
    }
    __syncthreads();
    // aggregation: u = oc*40 + dn, oc 0..15
    for (int u = tid; u < 16 * NPG; u += 256) {
        int oc = u / NPG, dn = u - oc * NPG;
        float a0=0,a1=0,a2=0,a3=0,a4=0,a5=0,a6=0,a7=0;
        for (int s = 0; s < NPG; s++) {
            float a = At[s * NPG + dn];
            uint4 pk = *(const uint4*)&h[s * HID + ((oc ^ (s & 7)) * 8)];
            a0 += a * lo16(pk.x); a1 += a * hi16(pk.x);
            a2 += a * lo16(pk.y); a3 += a * hi16(pk.y);
            a4 += a * lo16(pk.z); a5 += a * hi16(pk.z);
            a6 += a * lo16(pk.w); a7 += a * hi16(pk.w);
        }
        float vr[8] = {a0,a1,a2,a3,a4,a5,a6,a7};
        int ch = oc * 8;
        #pragma unroll
        for (int j = 0; j < 8; j++) {
            int c = ch + j;
            float o = vr[j] + bias[c];
            o = (o - bnm[c]) * rsqrtf(bnv[c] + BN_EPS) * bng[c] + bnb[c];
            ob[dn * 129 + c] = o;     // no relu
        }
    }
    __syncthreads();
    {   // pool: 256 threads = 128 ch x {mean,max}
        int c = tid & 127, which = tid >> 7;
        const float* bp = &ob[c];
        if (!which) {
            float s = 0.f;
            for (int i = 0; i < NPG; i++) s += bp[i * 129];
            cmb[(size_t)gg * 512 + colbase + c] = s * (1.f / NPG);
        } else {
            float m = -1e30f;
            for (int i = 0; i < NPG; i++) m = fmaxf(m, bp[i * 129]);
            cmb[(size_t)gg * 512 + colbase + HID + c] = m;
        }
    }
}

// ---------------------------------------------------------------------------
// Final MLP: [520] -> 256 (BN,ReLU) -> 128 (BN,ReLU) -> 1 (sigmoid), fp32
// ---------------------------------------------------------------------------
__global__ __launch_bounds__(256)
void mlp_kernel(const float* __restrict__ cmb, const float* __restrict__ addf,
                const float* __restrict__ W0, const float* __restrict__ b0,
                const float* __restrict__ g0v, const float* __restrict__ be0,
                const float* __restrict__ m0, const float* __restrict__ v0,
                const float* __restrict__ W1, const float* __restrict__ b1,
                const float* __restrict__ g1v, const float* __restrict__ be1,
                const float* __restrict__ m1, const float* __restrict__ v1,
                const float* __restrict__ W2, const float* __restrict__ b2,
                float* __restrict__ out)
{
    __shared__ float c[CMB];
    __shared__ float h1[256];
    __shared__ float h2[128];
    const int g = blockIdx.x, tid = threadIdx.x;
    for (int i = tid; i < 512; i += 256) c[i] = cmb[(size_t)g * 512 + i];
    if (tid < 8) c[512 + tid] = addf[g * 8 + tid];
    __syncthreads();
    {
        int j = tid;
        float acc = b0[j];
        for (int k = 0; k < CMB; k++) acc += c[k] * W0[k * 256 + j];
        acc = (acc - m0[j]) * rsqrtf(v0[j] + BN_EPS) * g0v[j] + be0[j];
        h1[j] = fmaxf(acc, 0.f);
    }
    __syncthreads();
    if (tid < 128) {
        int j = tid;
        float acc = b1[j];
        for (int k = 0; k < 256; k++) acc += h1[k] * W1[k * 128 + j];
        acc = (acc - m1[j]) * rsqrtf(v1[j] + BN_EPS) * g1v[j] + be1[j];
        h2[j] = fmaxf(acc, 0.f);
    }
    __syncthreads();
    if (tid == 0) {
        float acc = b2[0];
        for (int k = 0; k < 128; k++) acc += h2[k] * W2[k];
        out[g] = 1.f / (1.f + __expf(-acc));
    }
}

// ---------------------------------------------------------------------------
extern "C" void kernel_launch(void* const* d_in, const int* in_sizes, int n_in,
                              void* d_out, int out_size, void* d_ws, size_t ws_size,
                              hipStream_t stream)
{
    float* out = (float*)d_out;
    int out_n = out_size < 4096 ? out_size : 4096;

    const float* x_a  = (const float*)d_in[0];
    const int*   edge_a = (const int*)d_in[1];
    const float* x_b  = (const float*)d_in[3];
    const int*   edge_b = (const int*)d_in[4];
    const float* addf = (const float*)d_in[6];
    const float* gW0 = (const float*)d_in[7],  *gb0 = (const float*)d_in[8];
    const float* gas0 = (const float*)d_in[9], *gad0 = (const float*)d_in[10];
    const float* gW1 = (const float*)d_in[11], *gb1 = (const float*)d_in[12];
    const float* gas1 = (const float*)d_in[13], *gad1 = (const float*)d_in[14];
    const float* gW2 = (const float*)d_in[15], *gb2 = (const float*)d_in[16];
    const float* gas2 = (const float*)d_in[17], *gad2 = (const float*)d_in[18];
    const float* bn0g = (const float*)d_in[19], *bn0b = (const float*)d_in[20];
    const float* bn0m = (const float*)d_in[21], *bn0v = (const float*)d_in[22];
    const float* bn1g = (const float*)d_in[23], *bn1b = (const float*)d_in[24];
    const float* bn1m = (const float*)d_in[25], *bn1v = (const float*)d_in[26];
    const float* bn2g = (const float*)d_in[27], *bn2b = (const float*)d_in[28];
    const float* bn2m = (const float*)d_in[29], *bn2v = (const float*)d_in[30];
    const float* mW0 = (const float*)d_in[31], *mb0 = (const float*)d_in[32];
    const float* mg0 = (const float*)d_in[33], *mbe0 = (const float*)d_in[34];
    const float* mm0 = (const float*)d_in[35], *mv0 = (const float*)d_in[36];
    const float* mW1 = (const float*)d_in[37], *mb1 = (const float*)d_in[38];
    const float* mg1 = (const float*)d_in[39], *mbe1 = (const float*)d_in[40];
    const float* mm1 = (const float*)d_in[41], *mv1 = (const float*)d_in[42];
    const float* mW2 = (const float*)d_in[43], *mb2 = (const float*)d_in[44];

    // ---- workspace layout ----
    char* p = (char*)d_ws;
    const size_t CMB_BYTES = (size_t)B_GRAPHS * 512 * sizeof(float);   // 8 MB
    float* cmb = (float*)p; p += CMB_BYTES;
    unsigned short* W0t = (unsigned short*)p; p += (size_t)D0 * KP0 * 2;
    unsigned short* W1t = (unsigned short*)p; p += (size_t)D0 * D0 * 2;
    unsigned short* W2t = (unsigned short*)p; p += (size_t)HID * D0 * 2;
    size_t used = (size_t)(p - (char*)d_ws);
    const size_t PG = 7680ull + 40960ull + 40960ull;   // Xb + B1 + B2
    int chunk = B_GRAPHS;
    while (chunk > 4 && used + (size_t)chunk * PG > ws_size) chunk >>= 1;
    if (used + (size_t)chunk * PG > ws_size) {
        write_code_kernel<<<(out_n + 255) / 256, 256, 0, stream>>>(out, out_n, 500000.f);
        return;
    }
    unsigned short* Xb = (unsigned short*)p; p += (size_t)chunk * 7680;
    unsigned short* B1 = (unsigned short*)p; p += (size_t)chunk * 40960;
    unsigned short* B2 = (unsigned short*)p;

    // ---- weight conversion (once) ----
    convw_kernel<<<(D0 * KP0 + 255) / 256, 256, 0, stream>>>(gW0, W0t, F_IN, D0, KP0);
    convw_kernel<<<(D0 * D0 + 255) / 256, 256, 0, stream>>>(gW1, W1t, D0, D0, D0);
    convw_kernel<<<(HID * D0 + 255) / 256, 256, 0, stream>>>(gW2, W2t, D0, HID, D0);

    for (int drug = 0; drug < 2; drug++) {
        const float* x = drug ? x_b : x_a;
        const int* edge = drug ? edge_b : edge_a;
        int colbase = drug ? 256 : 0;

        for (int g0 = 0; g0 < B_GRAPHS; g0 += chunk) {
            int n = chunk * NPG;
            int gy = (n + 63) / 64;
            // layer 0
            convx_kernel<<<(n * KP0 + 255) / 256, 256, 0, stream>>>(
                x + (size_t)g0 * NPG * F_IN, Xb, n);
            gemm_mfma_kernel<<<dim3(D0 / 64, gy), 256, 0, stream>>>(
                Xb, W0t, B1, n, KP0, D0);
            gat4_fused_kernel<<<chunk, 256, 0, stream>>>(
                B1, edge, gas0, gad0, gb0, bn0g, bn0b, bn0m, bn0v, g0);
            // layer 1
            gemm_mfma_kernel<<<dim3(D0 / 64, gy), 256, 0, stream>>>(
                B1, W1t, B2, n, D0, D0);
            gat4_fused_kernel<<<chunk, 256, 0, stream>>>(
                B2, edge, gas1, gad1, gb1, bn1g, bn1b, bn1m, bn1v, g0);
            // layer 2
            gemm_mfma_kernel<<<dim3(HID / 64, gy), 256, 0, stream>>>(
                B2, W2t, B1, n, D0, HID);
            gat1_pool_fused_kernel<<<chunk, 256, 0, stream>>>(
                B1, edge, gas2, gad2, gb2, bn2g, bn2b, bn2m, bn2v,
                cmb, colbase, g0);
        }
    }
    mlp_kernel<<<B_GRAPHS, 256, 0, stream>>>(
        cmb, addf, mW0, mb0, mg0, mbe0, mm0, mv0,
        mW1, mb1, mg1, mbe1, mm1, mv1, mW2, mb2, out);
}